// Round 13
// baseline (880.175 us; speedup 1.0000x reference)
//
#include <hip/hip_runtime.h>
#include <hip/hip_fp16.h>
#include <math.h>

#define RCHUNK 8192            // edges per radix block
#define NBUCK 512              // max radix buckets (bucket = 256 dst)
#define CAP 12288              // LDS tmp capacity per bucket

typedef unsigned ev4 __attribute__((ext_vector_type(4)));

__device__ __forceinline__ float2 H2F(unsigned u) {
    __half2 h = *reinterpret_cast<__half2*>(&u);
    return __half22float2(h);
}
__device__ __forceinline__ unsigned F2H(float a, float b) {
    __half2 h = __floats2half2_rn(a, b);
    return *reinterpret_cast<unsigned*>(&h);
}

// unpack 8 fp16 edge attrs (non-temporal stream read)
__device__ __forceinline__ void loadA_nt(const __half* p, float* a) {
    ev4 u = __builtin_nontemporal_load((const ev4*)p);
    float2 t;
    t = H2F(u.x); a[0] = t.x; a[1] = t.y;
    t = H2F(u.y); a[2] = t.x; a[3] = t.y;
    t = H2F(u.z); a[4] = t.x; a[5] = t.y;
    t = H2F(u.w); a[6] = t.x; a[7] = t.y;
}

// packed per-head K/V fp16 packet
template<int C>
__device__ __forceinline__ void loadKV(const __half* p, float* k, float* v) {
    if constexpr (C == 6) {
        uint4 p0 = *(const uint4*)p;
        uint4 p1 = *(const uint4*)(p + 8);
        float2 t;
        t = H2F(p0.x); k[0] = t.x; k[1] = t.y;
        t = H2F(p0.y); k[2] = t.x; k[3] = t.y;
        t = H2F(p0.z); k[4] = t.x; k[5] = t.y;
        t = H2F(p0.w); v[0] = t.x; v[1] = t.y;
        t = H2F(p1.x); v[2] = t.x; v[3] = t.y;
        t = H2F(p1.y); v[4] = t.x; v[5] = t.y;
    } else {  // C == 3
        uint4 p0 = *(const uint4*)p;
        float2 t;
        t = H2F(p0.x); k[0] = t.x; k[1] = t.y;
        t = H2F(p0.y); k[2] = t.x; v[0] = t.y;
        t = H2F(p0.z); v[1] = t.x; v[2] = t.y;
    }
}

// ---- pass 1: per-block histogram over 512 buckets (LDS atomics only) ----
__global__ void histA_kernel(const int* __restrict__ ei, int* __restrict__ hist,
                             int E, int nblk) {
    __shared__ int h[NBUCK];
    h[threadIdx.x] = 0;
    h[threadIdx.x + 256] = 0;
    __syncthreads();
    int base = blockIdx.x * RCHUNK;
#pragma unroll
    for (int r = 0; r < RCHUNK / 256; ++r) {
        int i = base + r * 256 + threadIdx.x;
        if (i < E) atomicAdd(&h[ei[E + i] >> 8], 1);
    }
    __syncthreads();
    hist[threadIdx.x * nblk + blockIdx.x] = h[threadIdx.x];
    hist[(threadIdx.x + 256) * nblk + blockIdx.x] = h[threadIdx.x + 256];
}

// ---- pass 2: per-bucket exclusive scan over blocks; total -> btot ----
__global__ void scanB_kernel(int* __restrict__ hist, int* __restrict__ btot, int nblk) {
    __shared__ int sm[1024];
    int b = blockIdx.x;
    int tid = threadIdx.x;
    int v = (tid < nblk) ? hist[b * nblk + tid] : 0;
    sm[tid] = v;
    __syncthreads();
    for (int off = 1; off < 1024; off <<= 1) {
        int t = (tid >= off) ? sm[tid - off] : 0;
        __syncthreads();
        sm[tid] += t;
        __syncthreads();
    }
    if (tid < nblk) hist[b * nblk + tid] = sm[tid] - v;   // exclusive
    if (tid == 1023) btot[b] = sm[1023];
}

// ---- pass 3: exclusive scan of bucket totals -> bbase ----
__global__ void scanC_kernel(const int* __restrict__ btot, int* __restrict__ bbase) {
    __shared__ int sm[NBUCK];
    int tid = threadIdx.x;
    int v = btot[tid];
    sm[tid] = v;
    __syncthreads();
    for (int off = 1; off < NBUCK; off <<= 1) {
        int t = (tid >= off) ? sm[tid - off] : 0;
        __syncthreads();
        sm[tid] += t;
        __syncthreads();
    }
    bbase[tid] = sm[tid] - v;
}

// ---- pass 4: reorder packed (dstlo<<24 | eid) into bucket-grouped array ----
__global__ void reorderB_kernel(const int* __restrict__ ei, const int* __restrict__ hist,
                                const int* __restrict__ bbase, unsigned* __restrict__ sorted,
                                int E, int nblk) {
    __shared__ int off[NBUCK];
    off[threadIdx.x] = bbase[threadIdx.x] + hist[threadIdx.x * nblk + blockIdx.x];
    off[threadIdx.x + 256] = bbase[threadIdx.x + 256] + hist[(threadIdx.x + 256) * nblk + blockIdx.x];
    __syncthreads();
    int base = blockIdx.x * RCHUNK;
#pragma unroll
    for (int r = 0; r < RCHUNK / 256; ++r) {
        int i = base + r * 256 + threadIdx.x;
        if (i < E) {
            int dst = ei[E + i];
            int k = atomicAdd(&off[dst >> 8], 1);
            sorted[k] = ((unsigned)(dst & 255) << 24) | (unsigned)i;
        }
    }
}

// ---- pass 5: per-bucket LDS counting sort -> rowptr + srcp + eap ----
__global__ __launch_bounds__(256) void bucketsort_kernel(
        const unsigned* __restrict__ sorted,
        const int* __restrict__ bbase, const int* __restrict__ btot,
        int* __restrict__ rowptr,
        const int* __restrict__ ei, const float* __restrict__ ea,
        int* __restrict__ srcp, __half* __restrict__ eap, int N, int E) {
    __shared__ int h[256];
    __shared__ int tmp[CAP];
    int b = blockIdx.x;
    int lo = b << 8;
    int s = bbase[b], cnt = btot[b];
    int tid = threadIdx.x;

    h[tid] = 0;
    __syncthreads();
    for (int i = tid; i < cnt; i += 256) atomicAdd(&h[sorted[s + i] >> 24], 1);
    __syncthreads();
    int v = h[tid];
    for (int off = 1; off < 256; off <<= 1) {
        int t = (tid >= off) ? h[tid - off] : 0;
        __syncthreads();
        h[tid] += t;
        __syncthreads();
    }
    int excl = h[tid] - v;
    int dst = lo + tid;
    if (dst < N) rowptr[dst] = s + excl;
    if (b == 0 && tid == 0) rowptr[N] = E;
    __syncthreads();
    h[tid] = excl;
    __syncthreads();
    for (int i = tid; i < cnt; i += 256) {
        unsigned p2 = sorted[s + i];
        int dl = p2 >> 24;
        int eid = p2 & 0xFFFFFF;
        int r = atomicAdd(&h[dl], 1);
        if (r < CAP) {
            tmp[r] = eid;
        } else {
            int slot = s + r;
            srcp[slot] = ei[eid];
            float4 a0 = *(const float4*)(ea + (size_t)eid * 8);
            float4 a1 = *(const float4*)(ea + (size_t)eid * 8 + 4);
            uint4 u;
            u.x = F2H(a0.x, a0.y); u.y = F2H(a0.z, a0.w);
            u.z = F2H(a1.x, a1.y); u.w = F2H(a1.z, a1.w);
            *(uint4*)(eap + (size_t)slot * 8) = u;
        }
    }
    __syncthreads();
    int m = cnt < CAP ? cnt : CAP;
    for (int j = tid; j < m; j += 256) {
        int eid = tmp[j];
        int slot = s + j;
        srcp[slot] = ei[eid];
        float4 a0 = *(const float4*)(ea + (size_t)eid * 8);
        float4 a1 = *(const float4*)(ea + (size_t)eid * 8 + 4);
        uint4 u;
        u.x = F2H(a0.x, a0.y); u.y = F2H(a0.z, a0.w);
        u.z = F2H(a1.x, a1.y); u.w = F2H(a1.z, a1.w);
        *(uint4*)(eap + (size_t)slot * 8) = u;
    }
}

// ------- projections, H=8 layers -------
template<int CIN, int C, int PK>
__global__ void proj8_kernel(const float* __restrict__ X,
                             const float* __restrict__ wq, const float* __restrict__ bq,
                             const float* __restrict__ wk, const float* __restrict__ bk,
                             const float* __restrict__ wv, const float* __restrict__ bv,
                             const float* __restrict__ wsk, const float* __restrict__ bsk,
                             float* __restrict__ Q, __half* __restrict__ KV,
                             float* __restrict__ S, int N)
{
    const int HC = 8 * C;
    int idx = blockIdx.x * blockDim.x + threadIdx.x;
    if (idx >= N * HC) return;
    int n = idx / HC;
    int c = idx - n * HC;
    int h = c / C;
    int cc = c - h * C;
    float q = bq[c], k = bk[c], v = bv[c], s = bsk[c];
    const float* xr = X + (size_t)n * CIN;
#pragma unroll
    for (int i = 0; i < CIN; ++i) {
        float xi = xr[i];
        q = fmaf(xi, wq[i * HC + c], q);
        k = fmaf(xi, wk[i * HC + c], k);
        v = fmaf(xi, wv[i * HC + c], v);
        s = fmaf(xi, wsk[i * HC + c], s);
    }
    Q[(size_t)n * HC + c] = q;
    __half* kp = KV + (size_t)n * (8 * PK) + h * PK;
    kp[cc] = __float2half_rn(k);
    kp[C + cc] = __float2half_rn(v);
    S[(size_t)n * HC + c] = s;
}

// ------- projection, layer3 -------
__global__ void proj64_kernel(const float* __restrict__ X,
                              const float* __restrict__ wq, const float* __restrict__ bq,
                              const float* __restrict__ wk, const float* __restrict__ bk,
                              const float* __restrict__ wv, const float* __restrict__ bv,
                              const float* __restrict__ wsk, const float* __restrict__ bsk,
                              float* __restrict__ Q, __half* __restrict__ K16,
                              __half* __restrict__ V16, float* __restrict__ S, int N)
{
    int idx = blockIdx.x * blockDim.x + threadIdx.x;
    if (idx >= N * 64) return;
    int n = idx >> 6;
    int c = idx & 63;
    float q = bq[c], k = bk[c], v = bv[c], s = bsk[c];
    const float* xr = X + (size_t)n * 24;
#pragma unroll
    for (int i = 0; i < 24; ++i) {
        float xi = xr[i];
        q = fmaf(xi, wq[i * 64 + c], q);
        k = fmaf(xi, wk[i * 64 + c], k);
        v = fmaf(xi, wv[i * 64 + c], v);
        s = fmaf(xi, wsk[i * 64 + c], s);
    }
    Q[idx] = q;
    K16[idx] = __float2half_rn(k);
    V16[idx] = __float2half_rn(v);
    S[idx] = s;
}

// ---- fused gather+gate, H=8: thread per (node, head); UNROLL=2 or 4 ----
template<int C, int PK, int UNR>
__global__ void gather8f_kernel(const int* __restrict__ rowptr,
                                const int* __restrict__ srcp,
                                const __half* __restrict__ eap,
                                const float* __restrict__ we,
                                const float* __restrict__ Q,
                                const __half* __restrict__ KV,
                                const float* __restrict__ S,
                                const float* __restrict__ wb,
                                float* __restrict__ OUT,
                                int N, float scale)
{
    const int HC = 8 * C;
    int tid = blockIdx.x * blockDim.x + threadIdx.x;
    int n = tid >> 3;
    int h = tid & 7;
    if (n >= N) return;

    float q[C];
    const float* Qp = Q + (size_t)n * HC + h * C;
#pragma unroll
    for (int c = 0; c < C; ++c) q[c] = Qp[c];

    float qe[8];
#pragma unroll
    for (int d = 0; d < 8; ++d) {
        float t = 0.f;
#pragma unroll
        for (int c = 0; c < C; ++c) t = fmaf(we[d * HC + h * C + c], q[c], t);
        qe[d] = t;
    }

    float num[C];
#pragma unroll
    for (int c = 0; c < C; ++c) num[c] = 0.f;
    float sacc[8];
#pragma unroll
    for (int d = 0; d < 8; ++d) sacc[d] = 0.f;
    float den = 0.f;

    int rs = rowptr[n], re = rowptr[n + 1];
    int j = rs;
    for (; j + UNR - 1 < re; j += UNR) {
        int se[UNR];
        float a[UNR][8], kk[UNR][C], vv[UNR][C];
#pragma unroll
        for (int u = 0; u < UNR; ++u) se[u] = __builtin_nontemporal_load(&srcp[j + u]);
#pragma unroll
        for (int u = 0; u < UNR; ++u) loadA_nt(eap + (size_t)(j + u) * 8, a[u]);
#pragma unroll
        for (int u = 0; u < UNR; ++u)
            loadKV<C>(KV + (size_t)se[u] * (8 * PK) + h * PK, kk[u], vv[u]);
        float ex[UNR];
#pragma unroll
        for (int u = 0; u < UNR; ++u) {
            float d0 = 0.f;
#pragma unroll
            for (int c = 0; c < C; ++c) d0 = fmaf(q[c], kk[u][c], d0);
            float qa = 0.f;
#pragma unroll
            for (int d = 0; d < 8; ++d) qa = fmaf(qe[d], a[u][d], qa);
            ex[u] = __expf((d0 + qa) * scale);
        }
#pragma unroll
        for (int u = 0; u < UNR; ++u) {
            den += ex[u];
#pragma unroll
            for (int c = 0; c < C; ++c) num[c] = fmaf(ex[u], vv[u][c], num[c]);
#pragma unroll
            for (int d = 0; d < 8; ++d) sacc[d] = fmaf(ex[u], a[u][d], sacc[d]);
        }
    }
    for (; j < re; ++j) {
        int s0 = srcp[j];
        float a0[8];
        loadA_nt(eap + (size_t)j * 8, a0);
        float k0[C], v0[C];
        loadKV<C>(KV + (size_t)s0 * (8 * PK) + h * PK, k0, v0);
        float d0 = 0.f;
#pragma unroll
        for (int c = 0; c < C; ++c) d0 = fmaf(q[c], k0[c], d0);
        float qa0 = 0.f;
#pragma unroll
        for (int d = 0; d < 8; ++d) qa0 = fmaf(qe[d], a0[d], qa0);
        float ex0 = __expf((d0 + qa0) * scale);
        den += ex0;
#pragma unroll
        for (int c = 0; c < C; ++c) num[c] = fmaf(ex0, v0[c], num[c]);
#pragma unroll
        for (int d = 0; d < 8; ++d) sacc[d] = fmaf(ex0, a0[d], sacc[d]);
    }

    float inv = 1.f / (den + 1e-16f);
    float outc[C], sc[C];
    float gd = 0.f;
#pragma unroll
    for (int c = 0; c < C; ++c) {
        float e_ = 0.f;
#pragma unroll
        for (int d = 0; d < 8; ++d) e_ = fmaf(we[d * HC + h * C + c], sacc[d], e_);
        float o = (num[c] + e_) * inv;
        float s_ = S[(size_t)n * HC + h * C + c];
        outc[c] = o;
        sc[c] = s_;
        gd += o * wb[h * C + c] + s_ * wb[HC + h * C + c] + (o - s_) * wb[2 * HC + h * C + c];
    }
    gd += __shfl_xor(gd, 1, 8);
    gd += __shfl_xor(gd, 2, 8);
    gd += __shfl_xor(gd, 4, 8);
    float g = 1.f / (1.f + __expf(-gd));
#pragma unroll
    for (int c = 0; c < C; ++c) {
        float hh = fmaxf(g * sc[c] + (1.f - g) * outc[c], 0.f);
        OUT[(size_t)n * HC + h * C + c] = hh;
    }
}

// ---- fused gather+gate+classifier, H=1,C=64: 8 lanes/node, 4-edge unroll ----
__global__ __launch_bounds__(256) void gather64f_kernel(
        const int* __restrict__ rowptr,
        const int* __restrict__ srcp,
        const __half* __restrict__ eap,
        const float* __restrict__ we,
        const float* __restrict__ Q,
        const __half* __restrict__ K16,
        const __half* __restrict__ V16,
        const float* __restrict__ S,
        const float* __restrict__ wb,
        const float* __restrict__ wc,
        const float* __restrict__ bc,
        float* __restrict__ OUT,
        int N, float scale)
{
    int grp = (blockIdx.x * blockDim.x + threadIdx.x) >> 3;   // node
    int l8 = threadIdx.x & 7;
    if (grp >= N) return;
    int c0 = l8 << 3;   // this lane's 8 channels

    float q[8];
    *(float4*)q       = *(const float4*)(Q + (size_t)grp * 64 + c0);
    *(float4*)(q + 4) = *(const float4*)(Q + (size_t)grp * 64 + c0 + 4);
    float qe[8];
#pragma unroll
    for (int d = 0; d < 8; ++d) {
        float4 w0 = *(const float4*)(we + d * 64 + c0);
        float4 w1 = *(const float4*)(we + d * 64 + c0 + 4);
        float t = w0.x * q[0];
        t = fmaf(w0.y, q[1], t); t = fmaf(w0.z, q[2], t); t = fmaf(w0.w, q[3], t);
        t = fmaf(w1.x, q[4], t); t = fmaf(w1.y, q[5], t); t = fmaf(w1.z, q[6], t);
        t = fmaf(w1.w, q[7], t);
        qe[d] = t;
    }

    float num[8];
#pragma unroll
    for (int c = 0; c < 8; ++c) num[c] = 0.f;
    float sacc[8];
#pragma unroll
    for (int d = 0; d < 8; ++d) sacc[d] = 0.f;
    float den = 0.f;

    int rs = rowptr[grp], re = rowptr[grp + 1];
    int j = rs;
    for (; j + 3 < re; j += 4) {
        int se[4];
        float a[4][8];
        uint4 ku[4], vu[4];
#pragma unroll
        for (int u = 0; u < 4; ++u) se[u] = __builtin_nontemporal_load(&srcp[j + u]);
#pragma unroll
        for (int u = 0; u < 4; ++u) loadA_nt(eap + (size_t)(j + u) * 8, a[u]);
#pragma unroll
        for (int u = 0; u < 4; ++u) {
            ku[u] = *(const uint4*)(K16 + (size_t)se[u] * 64 + c0);
            vu[u] = *(const uint4*)(V16 + (size_t)se[u] * 64 + c0);
        }
        float t[4];
#pragma unroll
        for (int u = 0; u < 4; ++u) {
            float2 k01 = H2F(ku[u].x), k23 = H2F(ku[u].y);
            float2 k45 = H2F(ku[u].z), k67 = H2F(ku[u].w);
            float tt = q[0] * k01.x;
            tt = fmaf(q[1], k01.y, tt); tt = fmaf(q[2], k23.x, tt);
            tt = fmaf(q[3], k23.y, tt); tt = fmaf(q[4], k45.x, tt);
            tt = fmaf(q[5], k45.y, tt); tt = fmaf(q[6], k67.x, tt);
            tt = fmaf(q[7], k67.y, tt);
#pragma unroll
            for (int d = 0; d < 8; ++d) tt = fmaf(qe[d], a[u][d], tt);
            t[u] = tt;
        }
#pragma unroll
        for (int off = 4; off > 0; off >>= 1) {
            t[0] += __shfl_xor(t[0], off, 8);
            t[1] += __shfl_xor(t[1], off, 8);
            t[2] += __shfl_xor(t[2], off, 8);
            t[3] += __shfl_xor(t[3], off, 8);
        }
#pragma unroll
        for (int u = 0; u < 4; ++u) {
            float ex = __expf(t[u] * scale);
            den += ex;
            float2 v01 = H2F(vu[u].x), v23 = H2F(vu[u].y);
            float2 v45 = H2F(vu[u].z), v67 = H2F(vu[u].w);
            num[0] = fmaf(ex, v01.x, num[0]);
            num[1] = fmaf(ex, v01.y, num[1]);
            num[2] = fmaf(ex, v23.x, num[2]);
            num[3] = fmaf(ex, v23.y, num[3]);
            num[4] = fmaf(ex, v45.x, num[4]);
            num[5] = fmaf(ex, v45.y, num[5]);
            num[6] = fmaf(ex, v67.x, num[6]);
            num[7] = fmaf(ex, v67.y, num[7]);
#pragma unroll
            for (int d = 0; d < 8; ++d) sacc[d] = fmaf(ex, a[u][d], sacc[d]);
        }
    }
    for (; j < re; ++j) {
        int s0 = srcp[j];
        float a0[8];
        loadA_nt(eap + (size_t)j * 8, a0);
        uint4 ku0 = *(const uint4*)(K16 + (size_t)s0 * 64 + c0);
        uint4 vu0 = *(const uint4*)(V16 + (size_t)s0 * 64 + c0);
        float2 k01 = H2F(ku0.x), k23 = H2F(ku0.y);
        float2 k45 = H2F(ku0.z), k67 = H2F(ku0.w);
        float t0 = q[0] * k01.x;
        t0 = fmaf(q[1], k01.y, t0); t0 = fmaf(q[2], k23.x, t0);
        t0 = fmaf(q[3], k23.y, t0); t0 = fmaf(q[4], k45.x, t0);
        t0 = fmaf(q[5], k45.y, t0); t0 = fmaf(q[6], k67.x, t0);
        t0 = fmaf(q[7], k67.y, t0);
#pragma unroll
        for (int d = 0; d < 8; ++d) t0 = fmaf(qe[d], a0[d], t0);
#pragma unroll
        for (int off = 4; off > 0; off >>= 1) t0 += __shfl_xor(t0, off, 8);
        float ex0 = __expf(t0 * scale);
        den += ex0;
        float2 v01 = H2F(vu0.x), v23 = H2F(vu0.y);
        float2 v45 = H2F(vu0.z), v67 = H2F(vu0.w);
        num[0] = fmaf(ex0, v01.x, num[0]);
        num[1] = fmaf(ex0, v01.y, num[1]);
        num[2] = fmaf(ex0, v23.x, num[2]);
        num[3] = fmaf(ex0, v23.y, num[3]);
        num[4] = fmaf(ex0, v45.x, num[4]);
        num[5] = fmaf(ex0, v45.y, num[5]);
        num[6] = fmaf(ex0, v67.x, num[6]);
        num[7] = fmaf(ex0, v67.y, num[7]);
#pragma unroll
        for (int d = 0; d < 8; ++d) sacc[d] = fmaf(ex0, a0[d], sacc[d]);
    }

    // num correction with freshly reloaded we columns
#pragma unroll
    for (int d = 0; d < 8; ++d) {
        float4 w0 = *(const float4*)(we + d * 64 + c0);
        float4 w1 = *(const float4*)(we + d * 64 + c0 + 4);
        num[0] = fmaf(w0.x, sacc[d], num[0]);
        num[1] = fmaf(w0.y, sacc[d], num[1]);
        num[2] = fmaf(w0.z, sacc[d], num[2]);
        num[3] = fmaf(w0.w, sacc[d], num[3]);
        num[4] = fmaf(w1.x, sacc[d], num[4]);
        num[5] = fmaf(w1.y, sacc[d], num[5]);
        num[6] = fmaf(w1.z, sacc[d], num[6]);
        num[7] = fmaf(w1.w, sacc[d], num[7]);
    }
    float inv = 1.f / (den + 1e-16f);
    float o[8], sv[8];
    *(float4*)sv       = *(const float4*)(S + (size_t)grp * 64 + c0);
    *(float4*)(sv + 4) = *(const float4*)(S + (size_t)grp * 64 + c0 + 4);
    float gd = 0.f;
#pragma unroll
    for (int c = 0; c < 8; ++c) {
        o[c] = num[c] * inv;
        gd += o[c] * wb[c0 + c] + sv[c] * wb[64 + c0 + c] + (o[c] - sv[c]) * wb[128 + c0 + c];
    }
#pragma unroll
    for (int off = 4; off > 0; off >>= 1) gd += __shfl_xor(gd, off, 8);
    float g = 1.f / (1.f + __expf(-gd));
    float t = 0.f;
#pragma unroll
    for (int c = 0; c < 8; ++c) {
        float hh = fmaxf(g * sv[c] + (1.f - g) * o[c], 0.f);
        t = fmaf(hh, wc[c0 + c], t);
    }
#pragma unroll
    for (int off = 4; off > 0; off >>= 1) t += __shfl_xor(t, off, 8);
    if (l8 == 0) OUT[grp] = t + bc[0];
}

extern "C" void kernel_launch(void* const* d_in, const int* in_sizes, int n_in,
                              void* d_out, int out_size, void* d_ws, size_t ws_size,
                              hipStream_t stream) {
    const float* x  = (const float*)d_in[0];
    const int*   ei = (const int*)d_in[1];
    const float* ea = (const float*)d_in[2];
    const int N = in_sizes[0] / 32;
    const int E = in_sizes[1] / 2;

    int p = 3;
    const float *wq1=(const float*)d_in[p+0], *bq1=(const float*)d_in[p+1],
                *wk1=(const float*)d_in[p+2], *bk1=(const float*)d_in[p+3],
                *wv1=(const float*)d_in[p+4], *bv1=(const float*)d_in[p+5],
                *we1=(const float*)d_in[p+6],
                *wsk1=(const float*)d_in[p+7], *bsk1=(const float*)d_in[p+8],
                *wb1=(const float*)d_in[p+9];
    p += 10;
    const float *wq2=(const float*)d_in[p+0], *bq2=(const float*)d_in[p+1],
                *wk2=(const float*)d_in[p+2], *bk2=(const float*)d_in[p+3],
                *wv2=(const float*)d_in[p+4], *bv2=(const float*)d_in[p+5],
                *we2=(const float*)d_in[p+6],
                *wsk2=(const float*)d_in[p+7], *bsk2=(const float*)d_in[p+8],
                *wb2=(const float*)d_in[p+9];
    p += 10;
    const float *wq3=(const float*)d_in[p+0], *bq3=(const float*)d_in[p+1],
                *wk3=(const float*)d_in[p+2], *bk3=(const float*)d_in[p+3],
                *wv3=(const float*)d_in[p+4], *bv3=(const float*)d_in[p+5],
                *we3=(const float*)d_in[p+6],
                *wsk3=(const float*)d_in[p+7], *bsk3=(const float*)d_in[p+8],
                *wb3=(const float*)d_in[p+9];
    p += 10;
    const float *wc = (const float*)d_in[p+0], *bc = (const float*)d_in[p+1];

    float* out = (float*)d_out;

    // ---- workspace layout ----
    float* ws = (float*)d_ws;
    float* Hb = ws;                               // N*48 fp32
    float* Qb = Hb + (size_t)N * 48;              // N*64 fp32
    float* Sb = Qb + (size_t)N * 64;              // N*64 fp32
    __half* KV16  = (__half*)(Sb + (size_t)N * 64);  // N*128 halfs
    __half* K3    = KV16;
    __half* V3    = KV16 + (size_t)N * 64;
    __half* eap16 = KV16 + (size_t)N * 128;       // E*8 halfs
    int* ip      = (int*)(eap16 + (size_t)E * 8);
    int* rowptr  = ip;                 // N+2
    int* btot    = rowptr + (N + 2);   // 512
    int* bbase   = btot + 512;         // 512
    int* srcp    = bbase + 512;        // E
    int* hist    = srcp + E;           // NBUCK * nblkR
    unsigned* sorted = (unsigned*)Qb;  // aliases Qb; consumed before proj writes

    const int BLK = 256;
    const int nblkR = (E + RCHUNK - 1) / RCHUNK;
    const int nbuckUsed = (N + 255) >> 8;

    // ---------------- radix bucket + LDS counting sort ----------------
    histA_kernel<<<nblkR, 256, 0, stream>>>(ei, hist, E, nblkR);
    scanB_kernel<<<NBUCK, 1024, 0, stream>>>(hist, btot, nblkR);
    scanC_kernel<<<1, NBUCK, 0, stream>>>(btot, bbase);
    reorderB_kernel<<<nblkR, 256, 0, stream>>>(ei, hist, bbase, sorted, E, nblkR);
    bucketsort_kernel<<<nbuckUsed, 256, 0, stream>>>(
        sorted, bbase, btot, rowptr, ei, ea, srcp, eap16, N, E);

    // ------- layer 1: cin=32, H=8, C=6 (PK=16), 2-edge unroll -------
    proj8_kernel<32,6,16><<<(N*48 + BLK-1)/BLK, BLK, 0, stream>>>(
        x, wq1,bq1, wk1,bk1, wv1,bv1, wsk1,bsk1, Qb, KV16, Sb, N);
    gather8f_kernel<6,16,2><<<(N*8 + BLK-1)/BLK, BLK, 0, stream>>>(
        rowptr, srcp, eap16, we1, Qb, KV16, Sb, wb1, Hb, N, 1.0f/sqrtf(6.0f));

    // ------- layer 2: cin=48, H=8, C=3 (PK=8), 4-edge unroll -------
    proj8_kernel<48,3,8><<<(N*24 + BLK-1)/BLK, BLK, 0, stream>>>(
        Hb, wq2,bq2, wk2,bk2, wv2,bv2, wsk2,bsk2, Qb, KV16, Sb, N);
    gather8f_kernel<3,8,4><<<(N*8 + BLK-1)/BLK, BLK, 0, stream>>>(
        rowptr, srcp, eap16, we2, Qb, KV16, Sb, wb2, Hb, N, 1.0f/sqrtf(3.0f));

    // ------- layer 3: cin=24, H=1, C=64, 8 lanes/node, 4-edge unroll -------
    proj64_kernel<<<(N*64 + BLK-1)/BLK, BLK, 0, stream>>>(
        Hb, wq3,bq3, wk3,bk3, wv3,bv3, wsk3,bsk3, Qb, K3, V3, Sb, N);
    gather64f_kernel<<<((size_t)N*8 + BLK-1)/BLK, BLK, 0, stream>>>(
        rowptr, srcp, eap16, we3, Qb, K3, V3, Sb, wb3, wc, bc, out, N, 1.0f/8.0f);
}

// Round 14
// 794.601 us; speedup vs baseline: 1.1077x; 1.1077x over previous
//
#include <hip/hip_runtime.h>
#include <hip/hip_fp16.h>
#include <math.h>

#define RCHUNK 8192            // edges per radix block
#define NBUCK 512              // max radix buckets (bucket = 256 dst)
#define CAP 12288              // LDS tmp capacity per bucket

__device__ __forceinline__ float2 H2F(unsigned u) {
    __half2 h = *reinterpret_cast<__half2*>(&u);
    return __half22float2(h);
}
__device__ __forceinline__ unsigned F2H(float a, float b) {
    __half2 h = __floats2half2_rn(a, b);
    return *reinterpret_cast<unsigned*>(&h);
}

// unpack 8 fp16 edge attrs
__device__ __forceinline__ void loadA(const __half* p, float* a) {
    uint4 u = *(const uint4*)p;
    float2 t;
    t = H2F(u.x); a[0] = t.x; a[1] = t.y;
    t = H2F(u.y); a[2] = t.x; a[3] = t.y;
    t = H2F(u.z); a[4] = t.x; a[5] = t.y;
    t = H2F(u.w); a[6] = t.x; a[7] = t.y;
}

// packed per-head K/V fp16 packet
template<int C>
__device__ __forceinline__ void loadKV(const __half* p, float* k, float* v) {
    if constexpr (C == 6) {
        uint4 p0 = *(const uint4*)p;
        uint4 p1 = *(const uint4*)(p + 8);
        float2 t;
        t = H2F(p0.x); k[0] = t.x; k[1] = t.y;
        t = H2F(p0.y); k[2] = t.x; k[3] = t.y;
        t = H2F(p0.z); k[4] = t.x; k[5] = t.y;
        t = H2F(p0.w); v[0] = t.x; v[1] = t.y;
        t = H2F(p1.x); v[2] = t.x; v[3] = t.y;
        t = H2F(p1.y); v[4] = t.x; v[5] = t.y;
    } else {  // C == 3
        uint4 p0 = *(const uint4*)p;
        float2 t;
        t = H2F(p0.x); k[0] = t.x; k[1] = t.y;
        t = H2F(p0.y); k[2] = t.x; v[0] = t.y;
        t = H2F(p0.z); v[1] = t.x; v[2] = t.y;
    }
}

// ---- pass 1: per-block histogram over 512 buckets (LDS atomics only) ----
__global__ void histA_kernel(const int* __restrict__ ei, int* __restrict__ hist,
                             int E, int nblk) {
    __shared__ int h[NBUCK];
    h[threadIdx.x] = 0;
    h[threadIdx.x + 256] = 0;
    __syncthreads();
    int base = blockIdx.x * RCHUNK;
#pragma unroll
    for (int r = 0; r < RCHUNK / 256; ++r) {
        int i = base + r * 256 + threadIdx.x;
        if (i < E) atomicAdd(&h[ei[E + i] >> 8], 1);
    }
    __syncthreads();
    hist[threadIdx.x * nblk + blockIdx.x] = h[threadIdx.x];
    hist[(threadIdx.x + 256) * nblk + blockIdx.x] = h[threadIdx.x + 256];
}

// ---- pass 2: per-bucket exclusive scan over blocks; total -> btot ----
__global__ void scanB_kernel(int* __restrict__ hist, int* __restrict__ btot, int nblk) {
    __shared__ int sm[1024];
    int b = blockIdx.x;
    int tid = threadIdx.x;
    int v = (tid < nblk) ? hist[b * nblk + tid] : 0;
    sm[tid] = v;
    __syncthreads();
    for (int off = 1; off < 1024; off <<= 1) {
        int t = (tid >= off) ? sm[tid - off] : 0;
        __syncthreads();
        sm[tid] += t;
        __syncthreads();
    }
    if (tid < nblk) hist[b * nblk + tid] = sm[tid] - v;   // exclusive
    if (tid == 1023) btot[b] = sm[1023];
}

// ---- pass 3: exclusive scan of bucket totals -> bbase ----
__global__ void scanC_kernel(const int* __restrict__ btot, int* __restrict__ bbase) {
    __shared__ int sm[NBUCK];
    int tid = threadIdx.x;
    int v = btot[tid];
    sm[tid] = v;
    __syncthreads();
    for (int off = 1; off < NBUCK; off <<= 1) {
        int t = (tid >= off) ? sm[tid - off] : 0;
        __syncthreads();
        sm[tid] += t;
        __syncthreads();
    }
    bbase[tid] = sm[tid] - v;
}

// ---- pass 4: reorder packed (dstlo<<24 | eid) into bucket-grouped array ----
__global__ void reorderB_kernel(const int* __restrict__ ei, const int* __restrict__ hist,
                                const int* __restrict__ bbase, unsigned* __restrict__ sorted,
                                int E, int nblk) {
    __shared__ int off[NBUCK];
    off[threadIdx.x] = bbase[threadIdx.x] + hist[threadIdx.x * nblk + blockIdx.x];
    off[threadIdx.x + 256] = bbase[threadIdx.x + 256] + hist[(threadIdx.x + 256) * nblk + blockIdx.x];
    __syncthreads();
    int base = blockIdx.x * RCHUNK;
#pragma unroll
    for (int r = 0; r < RCHUNK / 256; ++r) {
        int i = base + r * 256 + threadIdx.x;
        if (i < E) {
            int dst = ei[E + i];
            int k = atomicAdd(&off[dst >> 8], 1);
            sorted[k] = ((unsigned)(dst & 255) << 24) | (unsigned)i;
        }
    }
}

// ---- pass 5: per-bucket LDS counting sort -> rowptr + srcp + eap ----
__global__ __launch_bounds__(256) void bucketsort_kernel(
        const unsigned* __restrict__ sorted,
        const int* __restrict__ bbase, const int* __restrict__ btot,
        int* __restrict__ rowptr,
        const int* __restrict__ ei, const float* __restrict__ ea,
        int* __restrict__ srcp, __half* __restrict__ eap, int N, int E) {
    __shared__ int h[256];
    __shared__ int tmp[CAP];
    int b = blockIdx.x;
    int lo = b << 8;
    int s = bbase[b], cnt = btot[b];
    int tid = threadIdx.x;

    h[tid] = 0;
    __syncthreads();
    for (int i = tid; i < cnt; i += 256) atomicAdd(&h[sorted[s + i] >> 24], 1);
    __syncthreads();
    int v = h[tid];
    for (int off = 1; off < 256; off <<= 1) {
        int t = (tid >= off) ? h[tid - off] : 0;
        __syncthreads();
        h[tid] += t;
        __syncthreads();
    }
    int excl = h[tid] - v;
    int dst = lo + tid;
    if (dst < N) rowptr[dst] = s + excl;
    if (b == 0 && tid == 0) rowptr[N] = E;
    __syncthreads();
    h[tid] = excl;
    __syncthreads();
    for (int i = tid; i < cnt; i += 256) {
        unsigned p2 = sorted[s + i];
        int dl = p2 >> 24;
        int eid = p2 & 0xFFFFFF;
        int r = atomicAdd(&h[dl], 1);
        if (r < CAP) {
            tmp[r] = eid;
        } else {
            int slot = s + r;
            srcp[slot] = ei[eid];
            float4 a0 = *(const float4*)(ea + (size_t)eid * 8);
            float4 a1 = *(const float4*)(ea + (size_t)eid * 8 + 4);
            uint4 u;
            u.x = F2H(a0.x, a0.y); u.y = F2H(a0.z, a0.w);
            u.z = F2H(a1.x, a1.y); u.w = F2H(a1.z, a1.w);
            *(uint4*)(eap + (size_t)slot * 8) = u;
        }
    }
    __syncthreads();
    int m = cnt < CAP ? cnt : CAP;
    for (int j = tid; j < m; j += 256) {
        int eid = tmp[j];
        int slot = s + j;
        srcp[slot] = ei[eid];
        float4 a0 = *(const float4*)(ea + (size_t)eid * 8);
        float4 a1 = *(const float4*)(ea + (size_t)eid * 8 + 4);
        uint4 u;
        u.x = F2H(a0.x, a0.y); u.y = F2H(a0.z, a0.w);
        u.z = F2H(a1.x, a1.y); u.w = F2H(a1.z, a1.w);
        *(uint4*)(eap + (size_t)slot * 8) = u;
    }
}

// ------- projections, H=8 layers -------
template<int CIN, int C, int PK>
__global__ void proj8_kernel(const float* __restrict__ X,
                             const float* __restrict__ wq, const float* __restrict__ bq,
                             const float* __restrict__ wk, const float* __restrict__ bk,
                             const float* __restrict__ wv, const float* __restrict__ bv,
                             const float* __restrict__ wsk, const float* __restrict__ bsk,
                             float* __restrict__ Q, __half* __restrict__ KV,
                             float* __restrict__ S, int N)
{
    const int HC = 8 * C;
    int idx = blockIdx.x * blockDim.x + threadIdx.x;
    if (idx >= N * HC) return;
    int n = idx / HC;
    int c = idx - n * HC;
    int h = c / C;
    int cc = c - h * C;
    float q = bq[c], k = bk[c], v = bv[c], s = bsk[c];
    const float* xr = X + (size_t)n * CIN;
#pragma unroll
    for (int i = 0; i < CIN; ++i) {
        float xi = xr[i];
        q = fmaf(xi, wq[i * HC + c], q);
        k = fmaf(xi, wk[i * HC + c], k);
        v = fmaf(xi, wv[i * HC + c], v);
        s = fmaf(xi, wsk[i * HC + c], s);
    }
    Q[(size_t)n * HC + c] = q;
    __half* kp = KV + (size_t)n * (8 * PK) + h * PK;
    kp[cc] = __float2half_rn(k);
    kp[C + cc] = __float2half_rn(v);
    S[(size_t)n * HC + c] = s;
}

// ------- projection, layer3 -------
__global__ void proj64_kernel(const float* __restrict__ X,
                              const float* __restrict__ wq, const float* __restrict__ bq,
                              const float* __restrict__ wk, const float* __restrict__ bk,
                              const float* __restrict__ wv, const float* __restrict__ bv,
                              const float* __restrict__ wsk, const float* __restrict__ bsk,
                              float* __restrict__ Q, __half* __restrict__ K16,
                              __half* __restrict__ V16, float* __restrict__ S, int N)
{
    int idx = blockIdx.x * blockDim.x + threadIdx.x;
    if (idx >= N * 64) return;
    int n = idx >> 6;
    int c = idx & 63;
    float q = bq[c], k = bk[c], v = bv[c], s = bsk[c];
    const float* xr = X + (size_t)n * 24;
#pragma unroll
    for (int i = 0; i < 24; ++i) {
        float xi = xr[i];
        q = fmaf(xi, wq[i * 64 + c], q);
        k = fmaf(xi, wk[i * 64 + c], k);
        v = fmaf(xi, wv[i * 64 + c], v);
        s = fmaf(xi, wsk[i * 64 + c], s);
    }
    Q[idx] = q;
    K16[idx] = __float2half_rn(k);
    V16[idx] = __float2half_rn(v);
    S[idx] = s;
}

// ---- fused gather+gate, H=8: thread per (node, head); UNROLL=2 or 4 ----
template<int C, int PK, int UNR>
__global__ void gather8f_kernel(const int* __restrict__ rowptr,
                                const int* __restrict__ srcp,
                                const __half* __restrict__ eap,
                                const float* __restrict__ we,
                                const float* __restrict__ Q,
                                const __half* __restrict__ KV,
                                const float* __restrict__ S,
                                const float* __restrict__ wb,
                                float* __restrict__ OUT,
                                int N, float scale)
{
    const int HC = 8 * C;
    int tid = blockIdx.x * blockDim.x + threadIdx.x;
    int n = tid >> 3;
    int h = tid & 7;
    if (n >= N) return;

    float q[C];
    const float* Qp = Q + (size_t)n * HC + h * C;
#pragma unroll
    for (int c = 0; c < C; ++c) q[c] = Qp[c];

    float qe[8];
#pragma unroll
    for (int d = 0; d < 8; ++d) {
        float t = 0.f;
#pragma unroll
        for (int c = 0; c < C; ++c) t = fmaf(we[d * HC + h * C + c], q[c], t);
        qe[d] = t;
    }

    float num[C];
#pragma unroll
    for (int c = 0; c < C; ++c) num[c] = 0.f;
    float sacc[8];
#pragma unroll
    for (int d = 0; d < 8; ++d) sacc[d] = 0.f;
    float den = 0.f;

    int rs = rowptr[n], re = rowptr[n + 1];
    int j = rs;
    for (; j + UNR - 1 < re; j += UNR) {
        int se[UNR];
        float a[UNR][8], kk[UNR][C], vv[UNR][C];
#pragma unroll
        for (int u = 0; u < UNR; ++u) se[u] = srcp[j + u];
#pragma unroll
        for (int u = 0; u < UNR; ++u) loadA(eap + (size_t)(j + u) * 8, a[u]);
#pragma unroll
        for (int u = 0; u < UNR; ++u)
            loadKV<C>(KV + (size_t)se[u] * (8 * PK) + h * PK, kk[u], vv[u]);
        float ex[UNR];
#pragma unroll
        for (int u = 0; u < UNR; ++u) {
            float d0 = 0.f;
#pragma unroll
            for (int c = 0; c < C; ++c) d0 = fmaf(q[c], kk[u][c], d0);
            float qa = 0.f;
#pragma unroll
            for (int d = 0; d < 8; ++d) qa = fmaf(qe[d], a[u][d], qa);
            ex[u] = __expf((d0 + qa) * scale);
        }
#pragma unroll
        for (int u = 0; u < UNR; ++u) {
            den += ex[u];
#pragma unroll
            for (int c = 0; c < C; ++c) num[c] = fmaf(ex[u], vv[u][c], num[c]);
#pragma unroll
            for (int d = 0; d < 8; ++d) sacc[d] = fmaf(ex[u], a[u][d], sacc[d]);
        }
    }
    for (; j < re; ++j) {
        int s0 = srcp[j];
        float a0[8];
        loadA(eap + (size_t)j * 8, a0);
        float k0[C], v0[C];
        loadKV<C>(KV + (size_t)s0 * (8 * PK) + h * PK, k0, v0);
        float d0 = 0.f;
#pragma unroll
        for (int c = 0; c < C; ++c) d0 = fmaf(q[c], k0[c], d0);
        float qa0 = 0.f;
#pragma unroll
        for (int d = 0; d < 8; ++d) qa0 = fmaf(qe[d], a0[d], qa0);
        float ex0 = __expf((d0 + qa0) * scale);
        den += ex0;
#pragma unroll
        for (int c = 0; c < C; ++c) num[c] = fmaf(ex0, v0[c], num[c]);
#pragma unroll
        for (int d = 0; d < 8; ++d) sacc[d] = fmaf(ex0, a0[d], sacc[d]);
    }

    float inv = 1.f / (den + 1e-16f);
    float outc[C], sc[C];
    float gd = 0.f;
#pragma unroll
    for (int c = 0; c < C; ++c) {
        float e_ = 0.f;
#pragma unroll
        for (int d = 0; d < 8; ++d) e_ = fmaf(we[d * HC + h * C + c], sacc[d], e_);
        float o = (num[c] + e_) * inv;
        float s_ = S[(size_t)n * HC + h * C + c];
        outc[c] = o;
        sc[c] = s_;
        gd += o * wb[h * C + c] + s_ * wb[HC + h * C + c] + (o - s_) * wb[2 * HC + h * C + c];
    }
    gd += __shfl_xor(gd, 1, 8);
    gd += __shfl_xor(gd, 2, 8);
    gd += __shfl_xor(gd, 4, 8);
    float g = 1.f / (1.f + __expf(-gd));
#pragma unroll
    for (int c = 0; c < C; ++c) {
        float hh = fmaxf(g * sc[c] + (1.f - g) * outc[c], 0.f);
        OUT[(size_t)n * HC + h * C + c] = hh;
    }
}

// ---- fused gather+gate+classifier, H=1,C=64: 8 lanes/node, 4-edge unroll ----
__global__ __launch_bounds__(256) void gather64f_kernel(
        const int* __restrict__ rowptr,
        const int* __restrict__ srcp,
        const __half* __restrict__ eap,
        const float* __restrict__ we,
        const float* __restrict__ Q,
        const __half* __restrict__ K16,
        const __half* __restrict__ V16,
        const float* __restrict__ S,
        const float* __restrict__ wb,
        const float* __restrict__ wc,
        const float* __restrict__ bc,
        float* __restrict__ OUT,
        int N, float scale)
{
    int grp = (blockIdx.x * blockDim.x + threadIdx.x) >> 3;   // node
    int l8 = threadIdx.x & 7;
    if (grp >= N) return;
    int c0 = l8 << 3;   // this lane's 8 channels

    float q[8];
    *(float4*)q       = *(const float4*)(Q + (size_t)grp * 64 + c0);
    *(float4*)(q + 4) = *(const float4*)(Q + (size_t)grp * 64 + c0 + 4);
    float qe[8];
#pragma unroll
    for (int d = 0; d < 8; ++d) {
        float4 w0 = *(const float4*)(we + d * 64 + c0);
        float4 w1 = *(const float4*)(we + d * 64 + c0 + 4);
        float t = w0.x * q[0];
        t = fmaf(w0.y, q[1], t); t = fmaf(w0.z, q[2], t); t = fmaf(w0.w, q[3], t);
        t = fmaf(w1.x, q[4], t); t = fmaf(w1.y, q[5], t); t = fmaf(w1.z, q[6], t);
        t = fmaf(w1.w, q[7], t);
        qe[d] = t;
    }

    float num[8];
#pragma unroll
    for (int c = 0; c < 8; ++c) num[c] = 0.f;
    float sacc[8];
#pragma unroll
    for (int d = 0; d < 8; ++d) sacc[d] = 0.f;
    float den = 0.f;

    int rs = rowptr[grp], re = rowptr[grp + 1];
    int j = rs;
    for (; j + 3 < re; j += 4) {
        int se[4];
        float a[4][8];
        uint4 ku[4], vu[4];
#pragma unroll
        for (int u = 0; u < 4; ++u) se[u] = srcp[j + u];
#pragma unroll
        for (int u = 0; u < 4; ++u) loadA(eap + (size_t)(j + u) * 8, a[u]);
#pragma unroll
        for (int u = 0; u < 4; ++u) {
            ku[u] = *(const uint4*)(K16 + (size_t)se[u] * 64 + c0);
            vu[u] = *(const uint4*)(V16 + (size_t)se[u] * 64 + c0);
        }
        float t[4];
#pragma unroll
        for (int u = 0; u < 4; ++u) {
            float2 k01 = H2F(ku[u].x), k23 = H2F(ku[u].y);
            float2 k45 = H2F(ku[u].z), k67 = H2F(ku[u].w);
            float tt = q[0] * k01.x;
            tt = fmaf(q[1], k01.y, tt); tt = fmaf(q[2], k23.x, tt);
            tt = fmaf(q[3], k23.y, tt); tt = fmaf(q[4], k45.x, tt);
            tt = fmaf(q[5], k45.y, tt); tt = fmaf(q[6], k67.x, tt);
            tt = fmaf(q[7], k67.y, tt);
#pragma unroll
            for (int d = 0; d < 8; ++d) tt = fmaf(qe[d], a[u][d], tt);
            t[u] = tt;
        }
#pragma unroll
        for (int off = 4; off > 0; off >>= 1) {
            t[0] += __shfl_xor(t[0], off, 8);
            t[1] += __shfl_xor(t[1], off, 8);
            t[2] += __shfl_xor(t[2], off, 8);
            t[3] += __shfl_xor(t[3], off, 8);
        }
#pragma unroll
        for (int u = 0; u < 4; ++u) {
            float ex = __expf(t[u] * scale);
            den += ex;
            float2 v01 = H2F(vu[u].x), v23 = H2F(vu[u].y);
            float2 v45 = H2F(vu[u].z), v67 = H2F(vu[u].w);
            num[0] = fmaf(ex, v01.x, num[0]);
            num[1] = fmaf(ex, v01.y, num[1]);
            num[2] = fmaf(ex, v23.x, num[2]);
            num[3] = fmaf(ex, v23.y, num[3]);
            num[4] = fmaf(ex, v45.x, num[4]);
            num[5] = fmaf(ex, v45.y, num[5]);
            num[6] = fmaf(ex, v67.x, num[6]);
            num[7] = fmaf(ex, v67.y, num[7]);
#pragma unroll
            for (int d = 0; d < 8; ++d) sacc[d] = fmaf(ex, a[u][d], sacc[d]);
        }
    }
    for (; j < re; ++j) {
        int s0 = srcp[j];
        float a0[8];
        loadA(eap + (size_t)j * 8, a0);
        uint4 ku0 = *(const uint4*)(K16 + (size_t)s0 * 64 + c0);
        uint4 vu0 = *(const uint4*)(V16 + (size_t)s0 * 64 + c0);
        float2 k01 = H2F(ku0.x), k23 = H2F(ku0.y);
        float2 k45 = H2F(ku0.z), k67 = H2F(ku0.w);
        float t0 = q[0] * k01.x;
        t0 = fmaf(q[1], k01.y, t0); t0 = fmaf(q[2], k23.x, t0);
        t0 = fmaf(q[3], k23.y, t0); t0 = fmaf(q[4], k45.x, t0);
        t0 = fmaf(q[5], k45.y, t0); t0 = fmaf(q[6], k67.x, t0);
        t0 = fmaf(q[7], k67.y, t0);
#pragma unroll
        for (int d = 0; d < 8; ++d) t0 = fmaf(qe[d], a0[d], t0);
#pragma unroll
        for (int off = 4; off > 0; off >>= 1) t0 += __shfl_xor(t0, off, 8);
        float ex0 = __expf(t0 * scale);
        den += ex0;
        float2 v01 = H2F(vu0.x), v23 = H2F(vu0.y);
        float2 v45 = H2F(vu0.z), v67 = H2F(vu0.w);
        num[0] = fmaf(ex0, v01.x, num[0]);
        num[1] = fmaf(ex0, v01.y, num[1]);
        num[2] = fmaf(ex0, v23.x, num[2]);
        num[3] = fmaf(ex0, v23.y, num[3]);
        num[4] = fmaf(ex0, v45.x, num[4]);
        num[5] = fmaf(ex0, v45.y, num[5]);
        num[6] = fmaf(ex0, v67.x, num[6]);
        num[7] = fmaf(ex0, v67.y, num[7]);
#pragma unroll
        for (int d = 0; d < 8; ++d) sacc[d] = fmaf(ex0, a0[d], sacc[d]);
    }

    // num correction with freshly reloaded we columns
#pragma unroll
    for (int d = 0; d < 8; ++d) {
        float4 w0 = *(const float4*)(we + d * 64 + c0);
        float4 w1 = *(const float4*)(we + d * 64 + c0 + 4);
        num[0] = fmaf(w0.x, sacc[d], num[0]);
        num[1] = fmaf(w0.y, sacc[d], num[1]);
        num[2] = fmaf(w0.z, sacc[d], num[2]);
        num[3] = fmaf(w0.w, sacc[d], num[3]);
        num[4] = fmaf(w1.x, sacc[d], num[4]);
        num[5] = fmaf(w1.y, sacc[d], num[5]);
        num[6] = fmaf(w1.z, sacc[d], num[6]);
        num[7] = fmaf(w1.w, sacc[d], num[7]);
    }
    float inv = 1.f / (den + 1e-16f);
    float o[8], sv[8];
    *(float4*)sv       = *(const float4*)(S + (size_t)grp * 64 + c0);
    *(float4*)(sv + 4) = *(const float4*)(S + (size_t)grp * 64 + c0 + 4);
    float gd = 0.f;
#pragma unroll
    for (int c = 0; c < 8; ++c) {
        o[c] = num[c] * inv;
        gd += o[c] * wb[c0 + c] + sv[c] * wb[64 + c0 + c] + (o[c] - sv[c]) * wb[128 + c0 + c];
    }
#pragma unroll
    for (int off = 4; off > 0; off >>= 1) gd += __shfl_xor(gd, off, 8);
    float g = 1.f / (1.f + __expf(-gd));
    float t = 0.f;
#pragma unroll
    for (int c = 0; c < 8; ++c) {
        float hh = fmaxf(g * sv[c] + (1.f - g) * o[c], 0.f);
        t = fmaf(hh, wc[c0 + c], t);
    }
#pragma unroll
    for (int off = 4; off > 0; off >>= 1) t += __shfl_xor(t, off, 8);
    if (l8 == 0) OUT[grp] = t + bc[0];
}

extern "C" void kernel_launch(void* const* d_in, const int* in_sizes, int n_in,
                              void* d_out, int out_size, void* d_ws, size_t ws_size,
                              hipStream_t stream) {
    const float* x  = (const float*)d_in[0];
    const int*   ei = (const int*)d_in[1];
    const float* ea = (const float*)d_in[2];
    const int N = in_sizes[0] / 32;
    const int E = in_sizes[1] / 2;

    int p = 3;
    const float *wq1=(const float*)d_in[p+0], *bq1=(const float*)d_in[p+1],
                *wk1=(const float*)d_in[p+2], *bk1=(const float*)d_in[p+3],
                *wv1=(const float*)d_in[p+4], *bv1=(const float*)d_in[p+5],
                *we1=(const float*)d_in[p+6],
                *wsk1=(const float*)d_in[p+7], *bsk1=(const float*)d_in[p+8],
                *wb1=(const float*)d_in[p+9];
    p += 10;
    const float *wq2=(const float*)d_in[p+0], *bq2=(const float*)d_in[p+1],
                *wk2=(const float*)d_in[p+2], *bk2=(const float*)d_in[p+3],
                *wv2=(const float*)d_in[p+4], *bv2=(const float*)d_in[p+5],
                *we2=(const float*)d_in[p+6],
                *wsk2=(const float*)d_in[p+7], *bsk2=(const float*)d_in[p+8],
                *wb2=(const float*)d_in[p+9];
    p += 10;
    const float *wq3=(const float*)d_in[p+0], *bq3=(const float*)d_in[p+1],
                *wk3=(const float*)d_in[p+2], *bk3=(const float*)d_in[p+3],
                *wv3=(const float*)d_in[p+4], *bv3=(const float*)d_in[p+5],
                *we3=(const float*)d_in[p+6],
                *wsk3=(const float*)d_in[p+7], *bsk3=(const float*)d_in[p+8],
                *wb3=(const float*)d_in[p+9];
    p += 10;
    const float *wc = (const float*)d_in[p+0], *bc = (const float*)d_in[p+1];

    float* out = (float*)d_out;

    // ---- workspace layout ----
    float* ws = (float*)d_ws;
    float* Hb = ws;                               // N*48 fp32
    float* Qb = Hb + (size_t)N * 48;              // N*64 fp32
    float* Sb = Qb + (size_t)N * 64;              // N*64 fp32
    __half* KV16  = (__half*)(Sb + (size_t)N * 64);  // N*128 halfs
    __half* K3    = KV16;
    __half* V3    = KV16 + (size_t)N * 64;
    __half* eap16 = KV16 + (size_t)N * 128;       // E*8 halfs
    int* ip      = (int*)(eap16 + (size_t)E * 8);
    int* rowptr  = ip;                 // N+2
    int* btot    = rowptr + (N + 2);   // 512
    int* bbase   = btot + 512;         // 512
    int* srcp    = bbase + 512;        // E
    int* hist    = srcp + E;           // NBUCK * nblkR
    unsigned* sorted = (unsigned*)Qb;  // aliases Qb; consumed before proj writes

    const int BLK = 256;
    const int nblkR = (E + RCHUNK - 1) / RCHUNK;
    const int nbuckUsed = (N + 255) >> 8;

    // ---------------- radix bucket + LDS counting sort ----------------
    histA_kernel<<<nblkR, 256, 0, stream>>>(ei, hist, E, nblkR);
    scanB_kernel<<<NBUCK, 1024, 0, stream>>>(hist, btot, nblkR);
    scanC_kernel<<<1, NBUCK, 0, stream>>>(btot, bbase);
    reorderB_kernel<<<nblkR, 256, 0, stream>>>(ei, hist, bbase, sorted, E, nblkR);
    bucketsort_kernel<<<nbuckUsed, 256, 0, stream>>>(
        sorted, bbase, btot, rowptr, ei, ea, srcp, eap16, N, E);

    // ------- layer 1: cin=32, H=8, C=6 (PK=16), 2-edge unroll -------
    proj8_kernel<32,6,16><<<(N*48 + BLK-1)/BLK, BLK, 0, stream>>>(
        x, wq1,bq1, wk1,bk1, wv1,bv1, wsk1,bsk1, Qb, KV16, Sb, N);
    gather8f_kernel<6,16,2><<<(N*8 + BLK-1)/BLK, BLK, 0, stream>>>(
        rowptr, srcp, eap16, we1, Qb, KV16, Sb, wb1, Hb, N, 1.0f/sqrtf(6.0f));

    // ------- layer 2: cin=48, H=8, C=3 (PK=8), 4-edge unroll -------
    proj8_kernel<48,3,8><<<(N*24 + BLK-1)/BLK, BLK, 0, stream>>>(
        Hb, wq2,bq2, wk2,bk2, wv2,bv2, wsk2,bsk2, Qb, KV16, Sb, N);
    gather8f_kernel<3,8,4><<<(N*8 + BLK-1)/BLK, BLK, 0, stream>>>(
        rowptr, srcp, eap16, we2, Qb, KV16, Sb, wb2, Hb, N, 1.0f/sqrtf(3.0f));

    // ------- layer 3: cin=24, H=1, C=64, 8 lanes/node, 4-edge unroll -------
    proj64_kernel<<<(N*64 + BLK-1)/BLK, BLK, 0, stream>>>(
        Hb, wq3,bq3, wk3,bk3, wv3,bv3, wsk3,bsk3, Qb, K3, V3, Sb, N);
    gather64f_kernel<<<((size_t)N*8 + BLK-1)/BLK, BLK, 0, stream>>>(
        rowptr, srcp, eap16, we3, Qb, K3, V3, Sb, wb3, wc, bc, out, N, 1.0f/8.0f);
}

// Round 15
// 784.266 us; speedup vs baseline: 1.1223x; 1.0132x over previous
//
#include <hip/hip_runtime.h>
#include <hip/hip_fp16.h>
#include <math.h>

#define RCHUNK 8192            // edges per radix block
#define NBUCK 512              // max radix buckets (bucket = 256 dst)
#define CAP 12288              // LDS tmp capacity per bucket

__device__ __forceinline__ float2 H2F(unsigned u) {
    __half2 h = *reinterpret_cast<__half2*>(&u);
    return __half22float2(h);
}
__device__ __forceinline__ unsigned F2H(float a, float b) {
    __half2 h = __floats2half2_rn(a, b);
    return *reinterpret_cast<unsigned*>(&h);
}

// unpack 8 fp16 edge attrs
__device__ __forceinline__ void loadA(const __half* p, float* a) {
    uint4 u = *(const uint4*)p;
    float2 t;
    t = H2F(u.x); a[0] = t.x; a[1] = t.y;
    t = H2F(u.y); a[2] = t.x; a[3] = t.y;
    t = H2F(u.z); a[4] = t.x; a[5] = t.y;
    t = H2F(u.w); a[6] = t.x; a[7] = t.y;
}

// packed per-head K/V fp16 packet
template<int C>
__device__ __forceinline__ void loadKV(const __half* p, float* k, float* v) {
    if constexpr (C == 6) {
        uint4 p0 = *(const uint4*)p;
        uint4 p1 = *(const uint4*)(p + 8);
        float2 t;
        t = H2F(p0.x); k[0] = t.x; k[1] = t.y;
        t = H2F(p0.y); k[2] = t.x; k[3] = t.y;
        t = H2F(p0.z); k[4] = t.x; k[5] = t.y;
        t = H2F(p0.w); v[0] = t.x; v[1] = t.y;
        t = H2F(p1.x); v[2] = t.x; v[3] = t.y;
        t = H2F(p1.y); v[4] = t.x; v[5] = t.y;
    } else {  // C == 3
        uint4 p0 = *(const uint4*)p;
        float2 t;
        t = H2F(p0.x); k[0] = t.x; k[1] = t.y;
        t = H2F(p0.y); k[2] = t.x; v[0] = t.y;
        t = H2F(p0.z); v[1] = t.x; v[2] = t.y;
    }
}

// ---- pass 1: per-block histogram over 512 buckets (LDS atomics only) ----
__global__ void histA_kernel(const int* __restrict__ ei, int* __restrict__ hist,
                             int E, int nblk) {
    __shared__ int h[NBUCK];
    h[threadIdx.x] = 0;
    h[threadIdx.x + 256] = 0;
    __syncthreads();
    int base = blockIdx.x * RCHUNK;
#pragma unroll
    for (int r = 0; r < RCHUNK / 256; ++r) {
        int i = base + r * 256 + threadIdx.x;
        if (i < E) atomicAdd(&h[ei[E + i] >> 8], 1);
    }
    __syncthreads();
    hist[threadIdx.x * nblk + blockIdx.x] = h[threadIdx.x];
    hist[(threadIdx.x + 256) * nblk + blockIdx.x] = h[threadIdx.x + 256];
}

// ---- pass 2: per-bucket exclusive scan over blocks; total -> btot ----
__global__ void scanB_kernel(int* __restrict__ hist, int* __restrict__ btot, int nblk) {
    __shared__ int sm[1024];
    int b = blockIdx.x;
    int tid = threadIdx.x;
    int v = (tid < nblk) ? hist[b * nblk + tid] : 0;
    sm[tid] = v;
    __syncthreads();
    for (int off = 1; off < 1024; off <<= 1) {
        int t = (tid >= off) ? sm[tid - off] : 0;
        __syncthreads();
        sm[tid] += t;
        __syncthreads();
    }
    if (tid < nblk) hist[b * nblk + tid] = sm[tid] - v;   // exclusive
    if (tid == 1023) btot[b] = sm[1023];
}

// ---- pass 3: exclusive scan of bucket totals -> bbase ----
__global__ void scanC_kernel(const int* __restrict__ btot, int* __restrict__ bbase) {
    __shared__ int sm[NBUCK];
    int tid = threadIdx.x;
    int v = btot[tid];
    sm[tid] = v;
    __syncthreads();
    for (int off = 1; off < NBUCK; off <<= 1) {
        int t = (tid >= off) ? sm[tid - off] : 0;
        __syncthreads();
        sm[tid] += t;
        __syncthreads();
    }
    bbase[tid] = sm[tid] - v;
}

// ---- pass 4 (fused): blocks [0,nblk) reorder; blocks [nblk,..) proj layer-1 ----
// reorder: packed (dstlo<<24 | eid) into bucket-grouped array.
// proj: Q,S fp32; KV fp16 packed (C=6, PK=16) — independent of sort data.
__global__ void reorder_proj_kernel(const int* __restrict__ ei, const int* __restrict__ hist,
                                    const int* __restrict__ bbase, unsigned* __restrict__ sorted,
                                    int E, int nblk,
                                    const float* __restrict__ X,
                                    const float* __restrict__ wq, const float* __restrict__ bq,
                                    const float* __restrict__ wk, const float* __restrict__ bk,
                                    const float* __restrict__ wv, const float* __restrict__ bv,
                                    const float* __restrict__ wsk, const float* __restrict__ bsk,
                                    float* __restrict__ Q, __half* __restrict__ KV,
                                    float* __restrict__ S, int N)
{
    if (blockIdx.x < (unsigned)nblk) {
        __shared__ int off[NBUCK];
        off[threadIdx.x] = bbase[threadIdx.x] + hist[threadIdx.x * nblk + blockIdx.x];
        off[threadIdx.x + 256] = bbase[threadIdx.x + 256] + hist[(threadIdx.x + 256) * nblk + blockIdx.x];
        __syncthreads();
        int base = blockIdx.x * RCHUNK;
#pragma unroll
        for (int r = 0; r < RCHUNK / 256; ++r) {
            int i = base + r * 256 + threadIdx.x;
            if (i < E) {
                int dst = ei[E + i];
                int k = atomicAdd(&off[dst >> 8], 1);
                sorted[k] = ((unsigned)(dst & 255) << 24) | (unsigned)i;
            }
        }
        return;
    }
    // ---- proj layer-1: cin=32, C=6, PK=16 ----
    const int HC = 48;
    int idx = (blockIdx.x - nblk) * blockDim.x + threadIdx.x;
    if (idx >= N * HC) return;
    int n = idx / HC;
    int c = idx - n * HC;
    int h = c / 6;
    int cc = c - h * 6;
    float q = bq[c], k = bk[c], v = bv[c], s = bsk[c];
    const float* xr = X + (size_t)n * 32;
#pragma unroll
    for (int i = 0; i < 32; ++i) {
        float xi = xr[i];
        q = fmaf(xi, wq[i * HC + c], q);
        k = fmaf(xi, wk[i * HC + c], k);
        v = fmaf(xi, wv[i * HC + c], v);
        s = fmaf(xi, wsk[i * HC + c], s);
    }
    Q[(size_t)n * HC + c] = q;
    __half* kp = KV + (size_t)n * 128 + h * 16;
    kp[cc] = __float2half_rn(k);
    kp[6 + cc] = __float2half_rn(v);
    S[(size_t)n * HC + c] = s;
}

// ---- pass 5: per-bucket LDS counting sort -> rowptr + srcp + eap ----
__global__ __launch_bounds__(256) void bucketsort_kernel(
        const unsigned* __restrict__ sorted,
        const int* __restrict__ bbase, const int* __restrict__ btot,
        int* __restrict__ rowptr,
        const int* __restrict__ ei, const float* __restrict__ ea,
        int* __restrict__ srcp, __half* __restrict__ eap, int N, int E) {
    __shared__ int h[256];
    __shared__ int tmp[CAP];
    int b = blockIdx.x;
    int lo = b << 8;
    int s = bbase[b], cnt = btot[b];
    int tid = threadIdx.x;

    h[tid] = 0;
    __syncthreads();
    for (int i = tid; i < cnt; i += 256) atomicAdd(&h[sorted[s + i] >> 24], 1);
    __syncthreads();
    int v = h[tid];
    for (int off = 1; off < 256; off <<= 1) {
        int t = (tid >= off) ? h[tid - off] : 0;
        __syncthreads();
        h[tid] += t;
        __syncthreads();
    }
    int excl = h[tid] - v;
    int dst = lo + tid;
    if (dst < N) rowptr[dst] = s + excl;
    if (b == 0 && tid == 0) rowptr[N] = E;
    __syncthreads();
    h[tid] = excl;
    __syncthreads();
    for (int i = tid; i < cnt; i += 256) {
        unsigned p2 = sorted[s + i];
        int dl = p2 >> 24;
        int eid = p2 & 0xFFFFFF;
        int r = atomicAdd(&h[dl], 1);
        if (r < CAP) {
            tmp[r] = eid;
        } else {
            int slot = s + r;
            srcp[slot] = ei[eid];
            float4 a0 = *(const float4*)(ea + (size_t)eid * 8);
            float4 a1 = *(const float4*)(ea + (size_t)eid * 8 + 4);
            uint4 u;
            u.x = F2H(a0.x, a0.y); u.y = F2H(a0.z, a0.w);
            u.z = F2H(a1.x, a1.y); u.w = F2H(a1.z, a1.w);
            *(uint4*)(eap + (size_t)slot * 8) = u;
        }
    }
    __syncthreads();
    int m = cnt < CAP ? cnt : CAP;
    for (int j = tid; j < m; j += 256) {
        int eid = tmp[j];
        int slot = s + j;
        srcp[slot] = ei[eid];
        float4 a0 = *(const float4*)(ea + (size_t)eid * 8);
        float4 a1 = *(const float4*)(ea + (size_t)eid * 8 + 4);
        uint4 u;
        u.x = F2H(a0.x, a0.y); u.y = F2H(a0.z, a0.w);
        u.z = F2H(a1.x, a1.y); u.w = F2H(a1.z, a1.w);
        *(uint4*)(eap + (size_t)slot * 8) = u;
    }
}

// ------- projections, H=8 layers (generic; used for layer 2) -------
template<int CIN, int C, int PK>
__global__ void proj8_kernel(const float* __restrict__ X,
                             const float* __restrict__ wq, const float* __restrict__ bq,
                             const float* __restrict__ wk, const float* __restrict__ bk,
                             const float* __restrict__ wv, const float* __restrict__ bv,
                             const float* __restrict__ wsk, const float* __restrict__ bsk,
                             float* __restrict__ Q, __half* __restrict__ KV,
                             float* __restrict__ S, int N)
{
    const int HC = 8 * C;
    int idx = blockIdx.x * blockDim.x + threadIdx.x;
    if (idx >= N * HC) return;
    int n = idx / HC;
    int c = idx - n * HC;
    int h = c / C;
    int cc = c - h * C;
    float q = bq[c], k = bk[c], v = bv[c], s = bsk[c];
    const float* xr = X + (size_t)n * CIN;
#pragma unroll
    for (int i = 0; i < CIN; ++i) {
        float xi = xr[i];
        q = fmaf(xi, wq[i * HC + c], q);
        k = fmaf(xi, wk[i * HC + c], k);
        v = fmaf(xi, wv[i * HC + c], v);
        s = fmaf(xi, wsk[i * HC + c], s);
    }
    Q[(size_t)n * HC + c] = q;
    __half* kp = KV + (size_t)n * (8 * PK) + h * PK;
    kp[cc] = __float2half_rn(k);
    kp[C + cc] = __float2half_rn(v);
    S[(size_t)n * HC + c] = s;
}

// ------- projection, layer3: interleaved 256B KV row {k[64], v[64]} -------
__global__ void proj64_kernel(const float* __restrict__ X,
                              const float* __restrict__ wq, const float* __restrict__ bq,
                              const float* __restrict__ wk, const float* __restrict__ bk,
                              const float* __restrict__ wv, const float* __restrict__ bv,
                              const float* __restrict__ wsk, const float* __restrict__ bsk,
                              float* __restrict__ Q, __half* __restrict__ KV3,
                              float* __restrict__ S, int N)
{
    int idx = blockIdx.x * blockDim.x + threadIdx.x;
    if (idx >= N * 64) return;
    int n = idx >> 6;
    int c = idx & 63;
    float q = bq[c], k = bk[c], v = bv[c], s = bsk[c];
    const float* xr = X + (size_t)n * 24;
#pragma unroll
    for (int i = 0; i < 24; ++i) {
        float xi = xr[i];
        q = fmaf(xi, wq[i * 64 + c], q);
        k = fmaf(xi, wk[i * 64 + c], k);
        v = fmaf(xi, wv[i * 64 + c], v);
        s = fmaf(xi, wsk[i * 64 + c], s);
    }
    Q[idx] = q;
    __half* kp = KV3 + (size_t)n * 128;
    kp[c] = __float2half_rn(k);
    kp[64 + c] = __float2half_rn(v);
    S[idx] = s;
}

// ---- fused gather+gate, H=8: thread per (node, head); UNROLL=2 or 4 ----
template<int C, int PK, int UNR>
__global__ void gather8f_kernel(const int* __restrict__ rowptr,
                                const int* __restrict__ srcp,
                                const __half* __restrict__ eap,
                                const float* __restrict__ we,
                                const float* __restrict__ Q,
                                const __half* __restrict__ KV,
                                const float* __restrict__ S,
                                const float* __restrict__ wb,
                                float* __restrict__ OUT,
                                int N, float scale)
{
    const int HC = 8 * C;
    int tid = blockIdx.x * blockDim.x + threadIdx.x;
    int n = tid >> 3;
    int h = tid & 7;
    if (n >= N) return;

    float q[C];
    const float* Qp = Q + (size_t)n * HC + h * C;
#pragma unroll
    for (int c = 0; c < C; ++c) q[c] = Qp[c];

    float qe[8];
#pragma unroll
    for (int d = 0; d < 8; ++d) {
        float t = 0.f;
#pragma unroll
        for (int c = 0; c < C; ++c) t = fmaf(we[d * HC + h * C + c], q[c], t);
        qe[d] = t;
    }

    float num[C];
#pragma unroll
    for (int c = 0; c < C; ++c) num[c] = 0.f;
    float sacc[8];
#pragma unroll
    for (int d = 0; d < 8; ++d) sacc[d] = 0.f;
    float den = 0.f;

    int rs = rowptr[n], re = rowptr[n + 1];
    int j = rs;
    for (; j + UNR - 1 < re; j += UNR) {
        int se[UNR];
        float a[UNR][8], kk[UNR][C], vv[UNR][C];
#pragma unroll
        for (int u = 0; u < UNR; ++u) se[u] = srcp[j + u];
#pragma unroll
        for (int u = 0; u < UNR; ++u) loadA(eap + (size_t)(j + u) * 8, a[u]);
#pragma unroll
        for (int u = 0; u < UNR; ++u)
            loadKV<C>(KV + (size_t)se[u] * (8 * PK) + h * PK, kk[u], vv[u]);
        float ex[UNR];
#pragma unroll
        for (int u = 0; u < UNR; ++u) {
            float d0 = 0.f;
#pragma unroll
            for (int c = 0; c < C; ++c) d0 = fmaf(q[c], kk[u][c], d0);
            float qa = 0.f;
#pragma unroll
            for (int d = 0; d < 8; ++d) qa = fmaf(qe[d], a[u][d], qa);
            ex[u] = __expf((d0 + qa) * scale);
        }
#pragma unroll
        for (int u = 0; u < UNR; ++u) {
            den += ex[u];
#pragma unroll
            for (int c = 0; c < C; ++c) num[c] = fmaf(ex[u], vv[u][c], num[c]);
#pragma unroll
            for (int d = 0; d < 8; ++d) sacc[d] = fmaf(ex[u], a[u][d], sacc[d]);
        }
    }
    for (; j < re; ++j) {
        int s0 = srcp[j];
        float a0[8];
        loadA(eap + (size_t)j * 8, a0);
        float k0[C], v0[C];
        loadKV<C>(KV + (size_t)s0 * (8 * PK) + h * PK, k0, v0);
        float d0 = 0.f;
#pragma unroll
        for (int c = 0; c < C; ++c) d0 = fmaf(q[c], k0[c], d0);
        float qa0 = 0.f;
#pragma unroll
        for (int d = 0; d < 8; ++d) qa0 = fmaf(qe[d], a0[d], qa0);
        float ex0 = __expf((d0 + qa0) * scale);
        den += ex0;
#pragma unroll
        for (int c = 0; c < C; ++c) num[c] = fmaf(ex0, v0[c], num[c]);
#pragma unroll
        for (int d = 0; d < 8; ++d) sacc[d] = fmaf(ex0, a0[d], sacc[d]);
    }

    float inv = 1.f / (den + 1e-16f);
    float outc[C], sc[C];
    float gd = 0.f;
#pragma unroll
    for (int c = 0; c < C; ++c) {
        float e_ = 0.f;
#pragma unroll
        for (int d = 0; d < 8; ++d) e_ = fmaf(we[d * HC + h * C + c], sacc[d], e_);
        float o = (num[c] + e_) * inv;
        float s_ = S[(size_t)n * HC + h * C + c];
        outc[c] = o;
        sc[c] = s_;
        gd += o * wb[h * C + c] + s_ * wb[HC + h * C + c] + (o - s_) * wb[2 * HC + h * C + c];
    }
    gd += __shfl_xor(gd, 1, 8);
    gd += __shfl_xor(gd, 2, 8);
    gd += __shfl_xor(gd, 4, 8);
    float g = 1.f / (1.f + __expf(-gd));
#pragma unroll
    for (int c = 0; c < C; ++c) {
        float hh = fmaxf(g * sc[c] + (1.f - g) * outc[c], 0.f);
        OUT[(size_t)n * HC + h * C + c] = hh;
    }
}

// ---- fused gather+gate+classifier, H=1,C=64: 8 lanes/node, 4-edge unroll ----
// KV3: interleaved 256B rows {k[64], v[64]}
__global__ __launch_bounds__(256) void gather64f_kernel(
        const int* __restrict__ rowptr,
        const int* __restrict__ srcp,
        const __half* __restrict__ eap,
        const float* __restrict__ we,
        const float* __restrict__ Q,
        const __half* __restrict__ KV3,
        const float* __restrict__ S,
        const float* __restrict__ wb,
        const float* __restrict__ wc,
        const float* __restrict__ bc,
        float* __restrict__ OUT,
        int N, float scale)
{
    int grp = (blockIdx.x * blockDim.x + threadIdx.x) >> 3;   // node
    int l8 = threadIdx.x & 7;
    if (grp >= N) return;
    int c0 = l8 << 3;   // this lane's 8 channels

    float q[8];
    *(float4*)q       = *(const float4*)(Q + (size_t)grp * 64 + c0);
    *(float4*)(q + 4) = *(const float4*)(Q + (size_t)grp * 64 + c0 + 4);
    float qe[8];
#pragma unroll
    for (int d = 0; d < 8; ++d) {
        float4 w0 = *(const float4*)(we + d * 64 + c0);
        float4 w1 = *(const float4*)(we + d * 64 + c0 + 4);
        float t = w0.x * q[0];
        t = fmaf(w0.y, q[1], t); t = fmaf(w0.z, q[2], t); t = fmaf(w0.w, q[3], t);
        t = fmaf(w1.x, q[4], t); t = fmaf(w1.y, q[5], t); t = fmaf(w1.z, q[6], t);
        t = fmaf(w1.w, q[7], t);
        qe[d] = t;
    }

    float num[8];
#pragma unroll
    for (int c = 0; c < 8; ++c) num[c] = 0.f;
    float sacc[8];
#pragma unroll
    for (int d = 0; d < 8; ++d) sacc[d] = 0.f;
    float den = 0.f;

    int rs = rowptr[grp], re = rowptr[grp + 1];
    int j = rs;
    for (; j + 3 < re; j += 4) {
        int se[4];
        float a[4][8];
        uint4 ku[4], vu[4];
#pragma unroll
        for (int u = 0; u < 4; ++u) se[u] = srcp[j + u];
#pragma unroll
        for (int u = 0; u < 4; ++u) loadA(eap + (size_t)(j + u) * 8, a[u]);
#pragma unroll
        for (int u = 0; u < 4; ++u) {
            const __half* kvp = KV3 + (size_t)se[u] * 128;
            ku[u] = *(const uint4*)(kvp + c0);
            vu[u] = *(const uint4*)(kvp + 64 + c0);
        }
        float t[4];
#pragma unroll
        for (int u = 0; u < 4; ++u) {
            float2 k01 = H2F(ku[u].x), k23 = H2F(ku[u].y);
            float2 k45 = H2F(ku[u].z), k67 = H2F(ku[u].w);
            float tt = q[0] * k01.x;
            tt = fmaf(q[1], k01.y, tt); tt = fmaf(q[2], k23.x, tt);
            tt = fmaf(q[3], k23.y, tt); tt = fmaf(q[4], k45.x, tt);
            tt = fmaf(q[5], k45.y, tt); tt = fmaf(q[6], k67.x, tt);
            tt = fmaf(q[7], k67.y, tt);
#pragma unroll
            for (int d = 0; d < 8; ++d) tt = fmaf(qe[d], a[u][d], tt);
            t[u] = tt;
        }
#pragma unroll
        for (int off = 4; off > 0; off >>= 1) {
            t[0] += __shfl_xor(t[0], off, 8);
            t[1] += __shfl_xor(t[1], off, 8);
            t[2] += __shfl_xor(t[2], off, 8);
            t[3] += __shfl_xor(t[3], off, 8);
        }
#pragma unroll
        for (int u = 0; u < 4; ++u) {
            float ex = __expf(t[u] * scale);
            den += ex;
            float2 v01 = H2F(vu[u].x), v23 = H2F(vu[u].y);
            float2 v45 = H2F(vu[u].z), v67 = H2F(vu[u].w);
            num[0] = fmaf(ex, v01.x, num[0]);
            num[1] = fmaf(ex, v01.y, num[1]);
            num[2] = fmaf(ex, v23.x, num[2]);
            num[3] = fmaf(ex, v23.y, num[3]);
            num[4] = fmaf(ex, v45.x, num[4]);
            num[5] = fmaf(ex, v45.y, num[5]);
            num[6] = fmaf(ex, v67.x, num[6]);
            num[7] = fmaf(ex, v67.y, num[7]);
#pragma unroll
            for (int d = 0; d < 8; ++d) sacc[d] = fmaf(ex, a[u][d], sacc[d]);
        }
    }
    for (; j < re; ++j) {
        int s0 = srcp[j];
        float a0[8];
        loadA(eap + (size_t)j * 8, a0);
        const __half* kvp = KV3 + (size_t)s0 * 128;
        uint4 ku0 = *(const uint4*)(kvp + c0);
        uint4 vu0 = *(const uint4*)(kvp + 64 + c0);
        float2 k01 = H2F(ku0.x), k23 = H2F(ku0.y);
        float2 k45 = H2F(ku0.z), k67 = H2F(ku0.w);
        float t0 = q[0] * k01.x;
        t0 = fmaf(q[1], k01.y, t0); t0 = fmaf(q[2], k23.x, t0);
        t0 = fmaf(q[3], k23.y, t0); t0 = fmaf(q[4], k45.x, t0);
        t0 = fmaf(q[5], k45.y, t0); t0 = fmaf(q[6], k67.x, t0);
        t0 = fmaf(q[7], k67.y, t0);
#pragma unroll
        for (int d = 0; d < 8; ++d) t0 = fmaf(qe[d], a0[d], t0);
#pragma unroll
        for (int off = 4; off > 0; off >>= 1) t0 += __shfl_xor(t0, off, 8);
        float ex0 = __expf(t0 * scale);
        den += ex0;
        float2 v01 = H2F(vu0.x), v23 = H2F(vu0.y);
        float2 v45 = H2F(vu0.z), v67 = H2F(vu0.w);
        num[0] = fmaf(ex0, v01.x, num[0]);
        num[1] = fmaf(ex0, v01.y, num[1]);
        num[2] = fmaf(ex0, v23.x, num[2]);
        num[3] = fmaf(ex0, v23.y, num[3]);
        num[4] = fmaf(ex0, v45.x, num[4]);
        num[5] = fmaf(ex0, v45.y, num[5]);
        num[6] = fmaf(ex0, v67.x, num[6]);
        num[7] = fmaf(ex0, v67.y, num[7]);
#pragma unroll
        for (int d = 0; d < 8; ++d) sacc[d] = fmaf(ex0, a0[d], sacc[d]);
    }

    // num correction with freshly reloaded we columns
#pragma unroll
    for (int d = 0; d < 8; ++d) {
        float4 w0 = *(const float4*)(we + d * 64 + c0);
        float4 w1 = *(const float4*)(we + d * 64 + c0 + 4);
        num[0] = fmaf(w0.x, sacc[d], num[0]);
        num[1] = fmaf(w0.y, sacc[d], num[1]);
        num[2] = fmaf(w0.z, sacc[d], num[2]);
        num[3] = fmaf(w0.w, sacc[d], num[3]);
        num[4] = fmaf(w1.x, sacc[d], num[4]);
        num[5] = fmaf(w1.y, sacc[d], num[5]);
        num[6] = fmaf(w1.z, sacc[d], num[6]);
        num[7] = fmaf(w1.w, sacc[d], num[7]);
    }
    float inv = 1.f / (den + 1e-16f);
    float o[8], sv[8];
    *(float4*)sv       = *(const float4*)(S + (size_t)grp * 64 + c0);
    *(float4*)(sv + 4) = *(const float4*)(S + (size_t)grp * 64 + c0 + 4);
    float gd = 0.f;
#pragma unroll
    for (int c = 0; c < 8; ++c) {
        o[c] = num[c] * inv;
        gd += o[c] * wb[c0 + c] + sv[c] * wb[64 + c0 + c] + (o[c] - sv[c]) * wb[128 + c0 + c];
    }
#pragma unroll
    for (int off = 4; off > 0; off >>= 1) gd += __shfl_xor(gd, off, 8);
    float g = 1.f / (1.f + __expf(-gd));
    float t = 0.f;
#pragma unroll
    for (int c = 0; c < 8; ++c) {
        float hh = fmaxf(g * sv[c] + (1.f - g) * o[c], 0.f);
        t = fmaf(hh, wc[c0 + c], t);
    }
#pragma unroll
    for (int off = 4; off > 0; off >>= 1) t += __shfl_xor(t, off, 8);
    if (l8 == 0) OUT[grp] = t + bc[0];
}

extern "C" void kernel_launch(void* const* d_in, const int* in_sizes, int n_in,
                              void* d_out, int out_size, void* d_ws, size_t ws_size,
                              hipStream_t stream) {
    const float* x  = (const float*)d_in[0];
    const int*   ei = (const int*)d_in[1];
    const float* ea = (const float*)d_in[2];
    const int N = in_sizes[0] / 32;
    const int E = in_sizes[1] / 2;

    int p = 3;
    const float *wq1=(const float*)d_in[p+0], *bq1=(const float*)d_in[p+1],
                *wk1=(const float*)d_in[p+2], *bk1=(const float*)d_in[p+3],
                *wv1=(const float*)d_in[p+4], *bv1=(const float*)d_in[p+5],
                *we1=(const float*)d_in[p+6],
                *wsk1=(const float*)d_in[p+7], *bsk1=(const float*)d_in[p+8],
                *wb1=(const float*)d_in[p+9];
    p += 10;
    const float *wq2=(const float*)d_in[p+0], *bq2=(const float*)d_in[p+1],
                *wk2=(const float*)d_in[p+2], *bk2=(const float*)d_in[p+3],
                *wv2=(const float*)d_in[p+4], *bv2=(const float*)d_in[p+5],
                *we2=(const float*)d_in[p+6],
                *wsk2=(const float*)d_in[p+7], *bsk2=(const float*)d_in[p+8],
                *wb2=(const float*)d_in[p+9];
    p += 10;
    const float *wq3=(const float*)d_in[p+0], *bq3=(const float*)d_in[p+1],
                *wk3=(const float*)d_in[p+2], *bk3=(const float*)d_in[p+3],
                *wv3=(const float*)d_in[p+4], *bv3=(const float*)d_in[p+5],
                *we3=(const float*)d_in[p+6],
                *wsk3=(const float*)d_in[p+7], *bsk3=(const float*)d_in[p+8],
                *wb3=(const float*)d_in[p+9];
    p += 10;
    const float *wc = (const float*)d_in[p+0], *bc = (const float*)d_in[p+1];

    float* out = (float*)d_out;

    // ---- workspace layout ----
    float* ws = (float*)d_ws;
    float* Hb = ws;                               // N*48 fp32
    float* Qb = Hb + (size_t)N * 48;              // N*64 fp32
    float* Sb = Qb + (size_t)N * 64;              // N*64 fp32
    __half* KV16  = (__half*)(Sb + (size_t)N * 64);  // N*128 halfs (layers 1/2 KV; layer3 KV3)
    __half* KV3   = KV16;
    __half* eap16 = KV16 + (size_t)N * 128;       // E*8 halfs
    int* ip      = (int*)(eap16 + (size_t)E * 8);
    int* rowptr  = ip;                 // N+2
    int* btot    = rowptr + (N + 2);   // 512
    int* bbase   = btot + 512;         // 512
    int* srcp    = bbase + 512;        // E
    int* hist    = srcp + E;           // NBUCK * nblkR
    const int nblkR = (E + RCHUNK - 1) / RCHUNK;
    unsigned* sorted = (unsigned*)(hist + (size_t)NBUCK * nblkR);  // E (dedicated)

    const int BLK = 256;
    const int nbuckUsed = (N + 255) >> 8;

    // ---------------- radix bucket + LDS counting sort ----------------
    histA_kernel<<<nblkR, 256, 0, stream>>>(ei, hist, E, nblkR);
    scanB_kernel<<<NBUCK, 1024, 0, stream>>>(hist, btot, nblkR);
    scanC_kernel<<<1, NBUCK, 0, stream>>>(btot, bbase);
    // fused: reorder (blocks [0,nblkR)) + layer-1 projection (remaining blocks)
    {
        int projBlocks = (N * 48 + BLK - 1) / BLK;
        reorder_proj_kernel<<<nblkR + projBlocks, 256, 0, stream>>>(
            ei, hist, bbase, sorted, E, nblkR,
            x, wq1, bq1, wk1, bk1, wv1, bv1, wsk1, bsk1, Qb, KV16, Sb, N);
    }
    bucketsort_kernel<<<nbuckUsed, 256, 0, stream>>>(
        sorted, bbase, btot, rowptr, ei, ea, srcp, eap16, N, E);

    // ------- layer 1 gather: C=6, PK=16, 2-edge unroll -------
    gather8f_kernel<6,16,2><<<(N*8 + BLK-1)/BLK, BLK, 0, stream>>>(
        rowptr, srcp, eap16, we1, Qb, KV16, Sb, wb1, Hb, N, 1.0f/sqrtf(6.0f));

    // ------- layer 2: cin=48, C=3, PK=8, 4-edge unroll -------
    proj8_kernel<48,3,8><<<(N*24 + BLK-1)/BLK, BLK, 0, stream>>>(
        Hb, wq2,bq2, wk2,bk2, wv2,bv2, wsk2,bsk2, Qb, KV16, Sb, N);
    gather8f_kernel<3,8,4><<<(N*8 + BLK-1)/BLK, BLK, 0, stream>>>(
        rowptr, srcp, eap16, we2, Qb, KV16, Sb, wb2, Hb, N, 1.0f/sqrtf(3.0f));

    // ------- layer 3: cin=24, H=1, C=64; interleaved KV3; 8 lanes/node -------
    proj64_kernel<<<(N*64 + BLK-1)/BLK, BLK, 0, stream>>>(
        Hb, wq3,bq3, wk3,bk3, wv3,bv3, wsk3,bsk3, Qb, KV3, Sb, N);
    gather64f_kernel<<<((size_t)N*8 + BLK-1)/BLK, BLK, 0, stream>>>(
        rowptr, srcp, eap16, we3, Qb, KV3, Sb, wb3, wc, bc, out, N, 1.0f/8.0f);
}